// Round 1
// baseline (474.842 us; speedup 1.0000x reference)
//
#include <hip/hip_runtime.h>
#include <hip/hip_bf16.h>

typedef __attribute__((ext_vector_type(8))) short bf16x8;
typedef __attribute__((ext_vector_type(4))) float f32x4;
typedef unsigned short u16;

// Problem constants
constexpr int NR      = 4096;     // rows
constexpr int INF     = 1024;     // in_features
constexpr int HEAD_N  = 2002;     // head classes (2000 + 2 cluster slots)
constexpr int HEAD_NP = 2016;     // padded to /16
constexpr int C0_LO   = 2000, C0_HI = 10000;
constexpr int C0_N    = 8000;     // 8000 % 16 == 0
constexpr int C1_N    = 40257;
constexpr int C1_NP   = 40272;    // padded to /16
constexpr int K0      = 256;      // hsz cluster 0
constexpr int K1      = 64;       // hsz cluster 1
constexpr int IGNORE  = -1;

static __device__ __forceinline__ u16 f32_to_bf16(float f) {
    unsigned int u = __float_as_uint(f);
    return (u16)((u + 0x7FFFu + ((u >> 16) & 1u)) >> 16);
}

// ---------------- fp32 -> bf16 convert (grid-stride) ----------------
__global__ void cvt_f32_bf16(const float* __restrict__ src, u16* __restrict__ dst, int n) {
    int stride = gridDim.x * blockDim.x;
    for (int i = blockIdx.x * blockDim.x + threadIdx.x; i < n; i += stride)
        dst[i] = f32_to_bf16(src[i]);
}

// ---------------- proj GEMM: H[NR][N] = X[NR][K] @ P[N][K]^T ----------------
// One wave computes 16 rows x all N cols. Grid: NR/64 blocks of 4 waves.
template<int K, int N>
__global__ void proj_gemm(const u16* __restrict__ X, const u16* __restrict__ P,
                          float* __restrict__ HF, u16* __restrict__ HB) {
    const int wave = threadIdx.x >> 6;
    const int lane = threadIdx.x & 63;
    const int rowbase = blockIdx.x * 64 + wave * 16;
    const int arow = rowbase + (lane & 15);
    const int koff = (lane >> 4) * 8;
    constexpr int NC = N / 16;

    f32x4 acc[NC];
#pragma unroll
    for (int n = 0; n < NC; ++n) acc[n] = (f32x4){0.f, 0.f, 0.f, 0.f};

    for (int kf = 0; kf < K / 32; ++kf) {
        bf16x8 a = *(const bf16x8*)(X + (size_t)arow * K + kf * 32 + koff);
#pragma unroll
        for (int n = 0; n < NC; ++n) {
            bf16x8 b = *(const bf16x8*)(P + (size_t)(n * 16 + (lane & 15)) * K + kf * 32 + koff);
            acc[n] = __builtin_amdgcn_mfma_f32_16x16x32_bf16(a, b, acc[n], 0, 0, 0);
        }
    }
    const int drow = rowbase + (lane >> 4) * 4;
    const int dcol0 = lane & 15;
#pragma unroll
    for (int n = 0; n < NC; ++n) {
#pragma unroll
        for (int r = 0; r < 4; ++r) {
            float v = acc[n][r];
            size_t idx = (size_t)(drow + r) * N + n * 16 + dcol0;
            HF[idx] = v;
            HB[idx] = f32_to_bf16(v);
        }
    }
}

// ---------------- streaming sum-exp over logits = H @ W^T ----------------
// Wave owns 16*NSETS rows (A in registers), streams W rows (classes) in
// 16-class chunks; accumulates exp(logit) per row; atomicAdd per row.
// Grid: (NR/(64*NSETS), NSPLIT) ; class-chunk range per blockIdx.y.
template<int K, int NSETS>
__global__ void sumexp_kernel(const u16* __restrict__ H, const u16* __restrict__ W,
                              int nreal, int nchunks, int cps, float* __restrict__ SE) {
    const int wave = threadIdx.x >> 6;
    const int lane = threadIdx.x & 63;
    const int rowbase = (blockIdx.x * 4 + wave) * (16 * NSETS);
    const int koff = (lane >> 4) * 8;
    constexpr int NKF = K / 32;

    bf16x8 afr[NSETS][NKF];
#pragma unroll
    for (int s = 0; s < NSETS; ++s) {
        int arow = rowbase + s * 16 + (lane & 15);
#pragma unroll
        for (int kf = 0; kf < NKF; ++kf)
            afr[s][kf] = *(const bf16x8*)(H + (size_t)arow * K + kf * 32 + koff);
    }

    float part[NSETS][4];
#pragma unroll
    for (int s = 0; s < NSETS; ++s)
#pragma unroll
        for (int r = 0; r < 4; ++r) part[s][r] = 0.f;

    const int c0 = blockIdx.y * cps;
    const int c1 = min(c0 + cps, nchunks);
    const int mycls_off = lane & 15;

    for (int ch = c0; ch < c1; ++ch) {
        const int cls = ch * 16 + mycls_off;
        const u16* wrow = W + (size_t)cls * K + koff;
        bf16x8 bfr[NKF];
#pragma unroll
        for (int kf = 0; kf < NKF; ++kf)
            bfr[kf] = *(const bf16x8*)(wrow + kf * 32);
        f32x4 acc[NSETS];
#pragma unroll
        for (int s = 0; s < NSETS; ++s) acc[s] = (f32x4){0.f, 0.f, 0.f, 0.f};
#pragma unroll
        for (int s = 0; s < NSETS; ++s)
#pragma unroll
            for (int kf = 0; kf < NKF; ++kf)
                acc[s] = __builtin_amdgcn_mfma_f32_16x16x32_bf16(afr[s][kf], bfr[kf], acc[s], 0, 0, 0);
        if (cls < nreal) {
#pragma unroll
            for (int s = 0; s < NSETS; ++s)
#pragma unroll
                for (int r = 0; r < 4; ++r) part[s][r] += __expf(acc[s][r]);
        }
    }

    // reduce across the 16 lanes of each lane-group (same lane>>4)
#pragma unroll
    for (int m = 1; m < 16; m <<= 1) {
#pragma unroll
        for (int s = 0; s < NSETS; ++s)
#pragma unroll
            for (int r = 0; r < 4; ++r)
                part[s][r] += __shfl_xor(part[s][r], m, 64);
    }
    if ((lane & 15) == 0) {
        const int rb = rowbase + (lane >> 4) * 4;
#pragma unroll
        for (int s = 0; s < NSETS; ++s)
#pragma unroll
            for (int r = 0; r < 4; ++r)
                atomicAdd(&SE[rb + s * 16 + r], part[s][r]);
    }
}

// ---------------- per-row epilogue: target dots (fp32) + combine ----------------
__global__ void epilogue_kernel(const float* __restrict__ x, const int* __restrict__ tgt,
                                const float* __restrict__ head_w,
                                const float* __restrict__ out0, const float* __restrict__ out1,
                                const float* __restrict__ h0f, const float* __restrict__ h1f,
                                const float* __restrict__ se_head, const float* __restrict__ se_c0,
                                const float* __restrict__ se_c1,
                                float* __restrict__ rowlogp, float* __restrict__ rowvalid) {
    const int r = blockIdx.x;
    const int tid = threadIdx.x;
    const int t = tgt[r];
    const bool valid = (t != IGNORE);
    const int tc = valid ? t : 0;
    const int band = (tc < C0_LO) ? 0 : (tc < C0_HI) ? 1 : 2;
    const int headclass = (band == 0) ? tc : (C0_LO + band - 1);

    const float* xr = x + (size_t)r * INF;
    const float* wr = head_w + (size_t)headclass * INF;
    float p1 = 0.f;
    for (int k = tid; k < INF; k += 256) p1 += xr[k] * wr[k];

    float p2 = 0.f;
    if (band == 1) {
        const float* hr = h0f + (size_t)r * K0;
        const float* cr = out0 + (size_t)(tc - C0_LO) * K0;
        for (int k = tid; k < K0; k += 256) p2 += hr[k] * cr[k];
    } else if (band == 2) {
        const float* hr = h1f + (size_t)r * K1;
        const float* cr = out1 + (size_t)(tc - C0_HI) * K1;
        for (int k = tid; k < K1; k += 256) p2 += hr[k] * cr[k];
    }

    __shared__ float s1[256], s2[256];
    s1[tid] = p1; s2[tid] = p2;
    __syncthreads();
    for (int s = 128; s > 0; s >>= 1) {
        if (tid < s) { s1[tid] += s1[tid + s]; s2[tid] += s2[tid + s]; }
        __syncthreads();
    }
    if (tid == 0) {
        float logp = s1[0] - __logf(se_head[r]);
        if (band == 1)      logp += s2[0] - __logf(se_c0[r]);
        else if (band == 2) logp += s2[0] - __logf(se_c1[r]);
        rowlogp[r]  = valid ? logp : 0.f;
        rowvalid[r] = valid ? 1.f : 0.f;
    }
}

// ---------------- deterministic final reduce ----------------
__global__ void final_reduce(const float* __restrict__ rowlogp,
                             const float* __restrict__ rowvalid, float* __restrict__ out) {
    __shared__ float sl[256], sv[256];
    const int tid = threadIdx.x;
    float a = 0.f, b = 0.f;
    for (int i = tid; i < NR; i += 256) { a += rowlogp[i]; b += rowvalid[i]; }
    sl[tid] = a; sv[tid] = b;
    __syncthreads();
    for (int s = 128; s > 0; s >>= 1) {
        if (tid < s) { sl[tid] += sl[tid + s]; sv[tid] += sv[tid + s]; }
        __syncthreads();
    }
    if (tid == 0) out[0] = -sl[0] / sv[0];
}

extern "C" void kernel_launch(void* const* d_in, const int* in_sizes, int n_in,
                              void* d_out, int out_size, void* d_ws, size_t ws_size,
                              hipStream_t stream) {
    const float* x      = (const float*)d_in[0];
    const int*   tgt    = (const int*)d_in[1];
    const float* head_w = (const float*)d_in[2];
    const float* proj0  = (const float*)d_in[3];
    const float* out0   = (const float*)d_in[4];
    const float* proj1  = (const float*)d_in[5];
    const float* out1   = (const float*)d_in[6];
    float* loss = (float*)d_out;

    char* base = (char*)d_ws;
    size_t off = 0;
    auto alloc = [&](size_t bytes) { char* p = base + off; off += (bytes + 255) & ~(size_t)255; return p; };

    u16* xb  = (u16*)alloc((size_t)NR * INF * 2);
    u16* hwb = (u16*)alloc((size_t)HEAD_NP * INF * 2);
    u16* p0b = (u16*)alloc((size_t)K0 * INF * 2);
    u16* p1b = (u16*)alloc((size_t)K1 * INF * 2);
    u16* o0b = (u16*)alloc((size_t)C0_N * K0 * 2);
    u16* o1b = (u16*)alloc((size_t)C1_NP * K1 * 2);
    float* h0f = (float*)alloc((size_t)NR * K0 * 4);
    u16*   h0b = (u16*)alloc((size_t)NR * K0 * 2);
    float* h1f = (float*)alloc((size_t)NR * K1 * 4);
    u16*   h1b = (u16*)alloc((size_t)NR * K1 * 2);
    float* se_head = (float*)alloc((size_t)NR * 4);
    float* se_c0   = (float*)alloc((size_t)NR * 4);
    float* se_c1   = (float*)alloc((size_t)NR * 4);
    float* rowlogp  = (float*)alloc((size_t)NR * 4);
    float* rowvalid = (float*)alloc((size_t)NR * 4);

    // zero the three sum-exp accumulators (they are contiguous allocations,
    // but memset each to stay robust to alignment padding)
    hipMemsetAsync(se_head, 0, (size_t)NR * 4, stream);
    hipMemsetAsync(se_c0,   0, (size_t)NR * 4, stream);
    hipMemsetAsync(se_c1,   0, (size_t)NR * 4, stream);

    // convert inputs to bf16
    cvt_f32_bf16<<<1024, 256, 0, stream>>>(x,      xb,  NR * INF);
    cvt_f32_bf16<<<1024, 256, 0, stream>>>(head_w, hwb, HEAD_N * INF);
    cvt_f32_bf16<<<256,  256, 0, stream>>>(proj0,  p0b, K0 * INF);
    cvt_f32_bf16<<<128,  256, 0, stream>>>(proj1,  p1b, K1 * INF);
    cvt_f32_bf16<<<1024, 256, 0, stream>>>(out0,   o0b, C0_N * K0);
    cvt_f32_bf16<<<1024, 256, 0, stream>>>(out1,   o1b, C1_N * K1);

    // tail projections h0 = x@proj0^T, h1 = x@proj1^T
    proj_gemm<INF, K0><<<NR / 64, 256, 0, stream>>>(xb, p0b, h0f, h0b);
    proj_gemm<INF, K1><<<NR / 64, 256, 0, stream>>>(xb, p1b, h1f, h1b);

    // streaming sum-exp
    {   // head: K=1024, 2016/16 = 126 chunks, 8 splits -> cps=16
        dim3 g(NR / 64, 8);
        sumexp_kernel<INF, 1><<<g, 256, 0, stream>>>(xb, hwb, HEAD_N, HEAD_NP / 16, 16, se_head);
    }
    {   // cluster0: K=256, 500 chunks, 16 splits -> cps=32
        dim3 g(NR / 128, 16);
        sumexp_kernel<K0, 2><<<g, 256, 0, stream>>>(h0b, o0b, C0_N, C0_N / 16, 32, se_c0);
    }
    {   // cluster1: K=64, 2517 chunks, 16 splits -> cps=158
        dim3 g(NR / 128, 16);
        sumexp_kernel<K1, 2><<<g, 256, 0, stream>>>(h1b, o1b, C1_N, C1_NP / 16, 158, se_c1);
    }

    epilogue_kernel<<<NR, 256, 0, stream>>>(x, tgt, head_w, out0, out1, h0f, h1f,
                                            se_head, se_c0, se_c1, rowlogp, rowvalid);
    final_reduce<<<1, 256, 0, stream>>>(rowlogp, rowvalid, loss);
    (void)in_sizes; (void)n_in; (void)out_size; (void)ws_size;
}

// Round 2
// 194.559 us; speedup vs baseline: 2.4406x; 2.4406x over previous
//
#include <hip/hip_runtime.h>
#include <hip/hip_bf16.h>

typedef __attribute__((ext_vector_type(8))) short bf16x8;
typedef __attribute__((ext_vector_type(4))) float f32x4;
typedef unsigned short u16;

// Problem constants
constexpr int NR      = 4096;
constexpr int INF     = 1024;
constexpr int HEAD_N  = 2002;
constexpr int HEAD_NP = 2048;     // padded to 128-tile
constexpr int C0_LO   = 2000, C0_HI = 10000;
constexpr int C0_N    = 8000;
constexpr int C0_NP   = 8064;     // 63 tiles
constexpr int C1_N    = 40257;
constexpr int C1_NP   = 40320;    // 315 tiles
constexpr int K0      = 256;
constexpr int K1      = 64;
constexpr int PCAT    = 320;      // 256 + 64 concatenated proj rows
constexpr int PCAT_P  = 384;      // 3 tiles
constexpr int IGNORE  = -1;

static __device__ __forceinline__ u16 f32_to_bf16(float f) {
    unsigned int u = __float_as_uint(f);
    return (u16)((u + 0x7FFFu + ((u >> 16) & 1u)) >> 16);
}

static __device__ __forceinline__ void gload_lds16(const u16* g, u16* l) {
    __builtin_amdgcn_global_load_lds(
        (const __attribute__((address_space(1))) unsigned int*)g,
        (__attribute__((address_space(3))) unsigned int*)l, 16, 0, 0);
}

// ---------------- fp32 -> bf16 convert (grid-stride) ----------------
__global__ void cvt_f32_bf16(const float* __restrict__ src, u16* __restrict__ dst, int n) {
    int stride = gridDim.x * blockDim.x;
    for (int i = blockIdx.x * blockDim.x + threadIdx.x; i < n; i += stride)
        dst[i] = f32_to_bf16(src[i]);
}

// ---------------- fused 128x128 tile GEMM ----------------
// C[row][col] = A[row][:] . B[col][:]  (both K-major, NT)
// EXP=true : atomicAdd(OUTF[row], sum_cols exp(C))       (cols < nreal)
// EXP=false: OUTF[row*ldc+col] = C; OUTB[...] = bf16(C)  (cols < nreal)
// LDS: linear [128][64] bf16 tiles with 16B-slot XOR swizzle (slot ^ (row&7)):
// staged via global_load_lds (linear dest, pre-swizzled global source),
// read back with the same XOR -> 2-way (free) bank aliasing on ds_read_b128.
template<int K, bool EXP>
__launch_bounds__(256, 2)
__global__ void fused_tile(const u16* __restrict__ A, int lda,
                           const u16* __restrict__ B, int ldb, int nreal,
                           float* __restrict__ OUTF, u16* __restrict__ OUTB, int ldc)
{
    __shared__ u16 ldsA[128 * 64];
    __shared__ u16 ldsB[128 * 64];
    const int tid  = threadIdx.x;
    const int wid  = tid >> 6;
    const int lane = tid & 63;
    const int wr   = wid >> 1;       // wave row (0..1) -> 64 rows
    const int wc   = wid & 1;        // wave col (0..1) -> 64 cols
    const int row0 = blockIdx.x * 128;
    const int col0 = blockIdx.y * 128;

    f32x4 acc[4][4];
#pragma unroll
    for (int m = 0; m < 4; ++m)
#pragma unroll
        for (int n = 0; n < 4; ++n) acc[m][n] = (f32x4){0.f, 0.f, 0.f, 0.f};

    // staging geometry: chunk = 1KB = 8 rows of 64 bf16; 16 chunks per tile
    const int srow = lane >> 3;            // row within chunk (0..7)
    const int ssw  = (lane & 7) ^ srow;    // swizzled 16B slot within row

    for (int ks = 0; ks < K / 64; ++ks) {
        const int k0 = ks * 64;
#pragma unroll
        for (int q = 0; q < 4; ++q) {
            const int c   = q * 4 + wid;
            const int row = c * 8 + srow;
            gload_lds16(A + (size_t)(row0 + row) * lda + k0 + ssw * 8, ldsA + c * 512);
        }
#pragma unroll
        for (int q = 0; q < 4; ++q) {
            const int c   = q * 4 + wid;
            const int row = c * 8 + srow;
            gload_lds16(B + (size_t)(col0 + row) * ldb + k0 + ssw * 8, ldsB + c * 512);
        }
        __syncthreads();   // compiler drains vmcnt(0) before s_barrier

        const bf16x8* A8 = (const bf16x8*)ldsA;
        const bf16x8* B8 = (const bf16x8*)ldsB;
        bf16x8 af[4][2], bf[4][2];
#pragma unroll
        for (int m = 0; m < 4; ++m) {
            const int ar = wr * 64 + m * 16 + (lane & 15);
#pragma unroll
            for (int ksub = 0; ksub < 2; ++ksub) {
                const int slot = ksub * 4 + (lane >> 4);
                af[m][ksub] = A8[ar * 8 + (slot ^ (ar & 7))];
            }
        }
#pragma unroll
        for (int n = 0; n < 4; ++n) {
            const int br = wc * 64 + n * 16 + (lane & 15);
#pragma unroll
            for (int ksub = 0; ksub < 2; ++ksub) {
                const int slot = ksub * 4 + (lane >> 4);
                bf[n][ksub] = B8[br * 8 + (slot ^ (br & 7))];
            }
        }
#pragma unroll
        for (int ksub = 0; ksub < 2; ++ksub)
#pragma unroll
            for (int m = 0; m < 4; ++m)
#pragma unroll
                for (int n = 0; n < 4; ++n)
                    acc[m][n] = __builtin_amdgcn_mfma_f32_16x16x32_bf16(
                        af[m][ksub], bf[n][ksub], acc[m][n], 0, 0, 0);
        __syncthreads();
    }

    if (EXP) {
#pragma unroll
        for (int m = 0; m < 4; ++m) {
            f32x4 rs = (f32x4){0.f, 0.f, 0.f, 0.f};
#pragma unroll
            for (int n = 0; n < 4; ++n) {
                const int cls = col0 + wc * 64 + n * 16 + (lane & 15);
                if (cls < nreal) {
#pragma unroll
                    for (int r = 0; r < 4; ++r) rs[r] += __expf(acc[m][n][r]);
                }
            }
#pragma unroll
            for (int msk = 1; msk < 16; msk <<= 1) {
#pragma unroll
                for (int r = 0; r < 4; ++r) rs[r] += __shfl_xor(rs[r], msk, 64);
            }
            if ((lane & 15) == 0) {
                const int rb = row0 + wr * 64 + m * 16 + (lane >> 4) * 4;
#pragma unroll
                for (int r = 0; r < 4; ++r) atomicAdd(&OUTF[rb + r], rs[r]);
            }
        }
    } else {
#pragma unroll
        for (int m = 0; m < 4; ++m) {
#pragma unroll
            for (int n = 0; n < 4; ++n) {
                const int col = col0 + wc * 64 + n * 16 + (lane & 15);
                if (col < nreal) {
#pragma unroll
                    for (int r = 0; r < 4; ++r) {
                        const int row = row0 + wr * 64 + m * 16 + (lane >> 4) * 4 + r;
                        const float v = acc[m][n][r];
                        OUTF[(size_t)row * ldc + col] = v;
                        OUTB[(size_t)row * ldc + col] = f32_to_bf16(v);
                    }
                }
            }
        }
    }
}

// ---------------- per-row epilogue: target dots (fp32) + combine ----------------
__global__ void epilogue_kernel(const float* __restrict__ x, const int* __restrict__ tgt,
                                const float* __restrict__ head_w,
                                const float* __restrict__ out0, const float* __restrict__ out1,
                                const float* __restrict__ hcatf,
                                const float* __restrict__ se_head, const float* __restrict__ se_c0,
                                const float* __restrict__ se_c1,
                                float* __restrict__ rowlogp, float* __restrict__ rowvalid) {
    const int r = blockIdx.x;
    const int tid = threadIdx.x;
    const int t = tgt[r];
    const bool valid = (t != IGNORE);
    const int tc = valid ? t : 0;
    const int band = (tc < C0_LO) ? 0 : (tc < C0_HI) ? 1 : 2;
    const int headclass = (band == 0) ? tc : (C0_LO + band - 1);

    const float* xr = x + (size_t)r * INF;
    const float* wr = head_w + (size_t)headclass * INF;
    float p1 = 0.f;
    for (int k = tid; k < INF; k += 256) p1 += xr[k] * wr[k];

    float p2 = 0.f;
    if (band == 1) {
        const float* hr = hcatf + (size_t)r * PCAT;
        const float* cr = out0 + (size_t)(tc - C0_LO) * K0;
        for (int k = tid; k < K0; k += 256) p2 += hr[k] * cr[k];
    } else if (band == 2) {
        const float* hr = hcatf + (size_t)r * PCAT + 256;
        const float* cr = out1 + (size_t)(tc - C0_HI) * K1;
        for (int k = tid; k < K1; k += 256) p2 += hr[k] * cr[k];
    }

    __shared__ float s1[256], s2[256];
    s1[tid] = p1; s2[tid] = p2;
    __syncthreads();
    for (int s = 128; s > 0; s >>= 1) {
        if (tid < s) { s1[tid] += s1[tid + s]; s2[tid] += s2[tid + s]; }
        __syncthreads();
    }
    if (tid == 0) {
        float logp = s1[0] - __logf(se_head[r]);
        if (band == 1)      logp += s2[0] - __logf(se_c0[r]);
        else if (band == 2) logp += s2[0] - __logf(se_c1[r]);
        rowlogp[r]  = valid ? logp : 0.f;
        rowvalid[r] = valid ? 1.f : 0.f;
    }
}

// ---------------- deterministic final reduce ----------------
__global__ void final_reduce(const float* __restrict__ rowlogp,
                             const float* __restrict__ rowvalid, float* __restrict__ out) {
    __shared__ float sl[256], sv[256];
    const int tid = threadIdx.x;
    float a = 0.f, b = 0.f;
    for (int i = tid; i < NR; i += 256) { a += rowlogp[i]; b += rowvalid[i]; }
    sl[tid] = a; sv[tid] = b;
    __syncthreads();
    for (int s = 128; s > 0; s >>= 1) {
        if (tid < s) { sl[tid] += sl[tid + s]; sv[tid] += sv[tid + s]; }
        __syncthreads();
    }
    if (tid == 0) out[0] = -sl[0] / sv[0];
}

extern "C" void kernel_launch(void* const* d_in, const int* in_sizes, int n_in,
                              void* d_out, int out_size, void* d_ws, size_t ws_size,
                              hipStream_t stream) {
    const float* x      = (const float*)d_in[0];
    const int*   tgt    = (const int*)d_in[1];
    const float* head_w = (const float*)d_in[2];
    const float* proj0  = (const float*)d_in[3];
    const float* out0   = (const float*)d_in[4];
    const float* proj1  = (const float*)d_in[5];
    const float* out1   = (const float*)d_in[6];
    float* loss = (float*)d_out;

    char* base = (char*)d_ws;
    size_t off = 0;
    auto alloc = [&](size_t bytes) { char* p = base + off; off += (bytes + 255) & ~(size_t)255; return p; };

    u16* xb    = (u16*)alloc((size_t)NR * INF * 2);
    u16* hwb   = (u16*)alloc((size_t)HEAD_NP * INF * 2);
    u16* pcatb = (u16*)alloc((size_t)PCAT_P * INF * 2);
    u16* o0b   = (u16*)alloc((size_t)C0_NP * K0 * 2);
    u16* o1b   = (u16*)alloc((size_t)C1_NP * K1 * 2);
    float* hcatf = (float*)alloc((size_t)NR * PCAT * 4);
    u16*   hcatb = (u16*)alloc((size_t)NR * PCAT * 2);
    float* se_head = (float*)alloc((size_t)NR * 4);
    float* se_c0   = (float*)alloc((size_t)NR * 4);
    float* se_c1   = (float*)alloc((size_t)NR * 4);
    float* rowlogp  = (float*)alloc((size_t)NR * 4);
    float* rowvalid = (float*)alloc((size_t)NR * 4);

    hipMemsetAsync(se_head, 0, (size_t)NR * 4, stream);
    hipMemsetAsync(se_c0,   0, (size_t)NR * 4, stream);
    hipMemsetAsync(se_c1,   0, (size_t)NR * 4, stream);

    // convert inputs to bf16 (padded tile regions left stale -> masked by nreal)
    cvt_f32_bf16<<<1024, 256, 0, stream>>>(x,      xb,    NR * INF);
    cvt_f32_bf16<<<1024, 256, 0, stream>>>(head_w, hwb,   HEAD_N * INF);
    cvt_f32_bf16<<<256,  256, 0, stream>>>(proj0,  pcatb,             256 * INF);
    cvt_f32_bf16<<<128,  256, 0, stream>>>(proj1,  pcatb + 256 * INF,  64 * INF);
    cvt_f32_bf16<<<1024, 256, 0, stream>>>(out0,   o0b,   C0_N * K0);
    cvt_f32_bf16<<<1024, 256, 0, stream>>>(out1,   o1b,   C1_N * K1);

    // hcat = X @ [proj0;proj1]^T   (f32 + bf16), row stride PCAT
    fused_tile<INF, false><<<dim3(32, 3), 256, 0, stream>>>(
        xb, INF, pcatb, INF, PCAT, hcatf, hcatb, PCAT);

    // sum-exp per row, fused into tiled GEMMs
    fused_tile<INF, true><<<dim3(32, HEAD_NP / 128), 256, 0, stream>>>(
        xb, INF, hwb, INF, HEAD_N, se_head, nullptr, 0);
    fused_tile<K0, true><<<dim3(32, C0_NP / 128), 256, 0, stream>>>(
        hcatb, PCAT, o0b, K0, C0_N, se_c0, nullptr, 0);
    fused_tile<K1, true><<<dim3(32, C1_NP / 128), 256, 0, stream>>>(
        hcatb + 256, PCAT, o1b, K1, C1_N, se_c1, nullptr, 0);

    epilogue_kernel<<<NR, 256, 0, stream>>>(x, tgt, head_w, out0, out1, hcatf,
                                            se_head, se_c0, se_c1, rowlogp, rowvalid);
    final_reduce<<<1, 256, 0, stream>>>(rowlogp, rowvalid, loss);
    (void)in_sizes; (void)n_in; (void)out_size; (void)ws_size;
}

// Round 3
// 116.624 us; speedup vs baseline: 4.0715x; 1.6683x over previous
//
#include <hip/hip_runtime.h>
#include <hip/hip_bf16.h>

typedef __attribute__((ext_vector_type(8))) short bf16x8;
typedef __attribute__((ext_vector_type(4))) float f32x4;
typedef unsigned short u16;

// Problem constants
constexpr int NR      = 4096;
constexpr int INF     = 1024;
constexpr int HEAD_N  = 2002;
constexpr int HEAD_NP = 2048;     // 16 col-tiles of 128
constexpr int C0_LO   = 2000, C0_HI = 10000;
constexpr int C0_N    = 8000;
constexpr int C0_NP   = 8064;
constexpr int C1_N    = 40257;
constexpr int C1_NP   = 40320;
constexpr int K0      = 256;
constexpr int K1      = 64;
constexpr int PCAT    = 320;      // 256 + 64 concatenated proj rows
constexpr int PCAT_P  = 384;      // 3 col-tiles of 128
constexpr int WCAT_R  = HEAD_NP + PCAT_P;  // 2432 rows in merged B
constexpr int IGNORE  = -1;

static __device__ __forceinline__ u16 f32_to_bf16(float f) {
    unsigned int u = __float_as_uint(f);
    return (u16)((u + 0x7FFFu + ((u >> 16) & 1u)) >> 16);
}

static __device__ __forceinline__ void gload_lds16(const u16* g, u16* l) {
    __builtin_amdgcn_global_load_lds(
        (const __attribute__((address_space(1))) unsigned int*)g,
        (__attribute__((address_space(3))) unsigned int*)l, 16, 0, 0);
}

// ---------------- fused multi-segment fp32 -> bf16 convert ----------------
struct CvtSegs { const float* s[6]; u16* d[6]; int n8[6]; };

__global__ void cvt_multi(CvtSegs segs) {
    const int stride = gridDim.x * blockDim.x;
    const int gid = blockIdx.x * blockDim.x + threadIdx.x;
#pragma unroll
    for (int seg = 0; seg < 6; ++seg) {
        const float4* sp = (const float4*)segs.s[seg];
        bf16x8* dp = (bf16x8*)segs.d[seg];
        const int n8 = segs.n8[seg];
        for (int i = gid; i < n8; i += stride) {
            float4 a = sp[2 * i], b = sp[2 * i + 1];
            bf16x8 o;
            o[0] = (short)f32_to_bf16(a.x); o[1] = (short)f32_to_bf16(a.y);
            o[2] = (short)f32_to_bf16(a.z); o[3] = (short)f32_to_bf16(a.w);
            o[4] = (short)f32_to_bf16(b.x); o[5] = (short)f32_to_bf16(b.y);
            o[6] = (short)f32_to_bf16(b.z); o[7] = (short)f32_to_bf16(b.w);
            dp[i] = o;
        }
    }
}

// ---------------- merged head+proj 128x128 tile GEMM (K=1024) ----------------
// blockIdx.y < 16 : head col-tile -> exp-sum epilogue into SEH (cols < HEAD_N)
// blockIdx.y >= 16: proj col-tile -> store f32+bf16 into hcat  (cols < PCAT)
__launch_bounds__(256, 2)
__global__ void fused_headproj(const u16* __restrict__ A, const u16* __restrict__ B,
                               float* __restrict__ SEH,
                               float* __restrict__ HF, u16* __restrict__ HB)
{
    constexpr int K = INF;
    __shared__ u16 ldsA[128 * 64];
    __shared__ u16 ldsB[128 * 64];
    const int tid  = threadIdx.x;
    const int wid  = tid >> 6;
    const int lane = tid & 63;
    const int wr   = wid >> 1;
    const int wc   = wid & 1;
    const int row0 = blockIdx.x * 128;
    const int col0 = blockIdx.y * 128;
    const bool expmode = (blockIdx.y < HEAD_NP / 128);

    f32x4 acc[4][4];
#pragma unroll
    for (int m = 0; m < 4; ++m)
#pragma unroll
        for (int n = 0; n < 4; ++n) acc[m][n] = (f32x4){0.f, 0.f, 0.f, 0.f};

    const int srow = lane >> 3;
    const int ssw  = (lane & 7) ^ srow;

    for (int ks = 0; ks < K / 64; ++ks) {
        const int k0 = ks * 64;
#pragma unroll
        for (int q = 0; q < 4; ++q) {
            const int c   = q * 4 + wid;
            const int row = c * 8 + srow;
            gload_lds16(A + (size_t)(row0 + row) * K + k0 + ssw * 8, ldsA + c * 512);
        }
#pragma unroll
        for (int q = 0; q < 4; ++q) {
            const int c   = q * 4 + wid;
            const int row = c * 8 + srow;
            gload_lds16(B + (size_t)(col0 + row) * K + k0 + ssw * 8, ldsB + c * 512);
        }
        __syncthreads();

        const bf16x8* A8 = (const bf16x8*)ldsA;
        const bf16x8* B8 = (const bf16x8*)ldsB;
        bf16x8 af[4][2], bf[4][2];
#pragma unroll
        for (int m = 0; m < 4; ++m) {
            const int ar = wr * 64 + m * 16 + (lane & 15);
#pragma unroll
            for (int ksub = 0; ksub < 2; ++ksub) {
                const int slot = ksub * 4 + (lane >> 4);
                af[m][ksub] = A8[ar * 8 + (slot ^ (ar & 7))];
            }
        }
#pragma unroll
        for (int n = 0; n < 4; ++n) {
            const int br = wc * 64 + n * 16 + (lane & 15);
#pragma unroll
            for (int ksub = 0; ksub < 2; ++ksub) {
                const int slot = ksub * 4 + (lane >> 4);
                bf[n][ksub] = B8[br * 8 + (slot ^ (br & 7))];
            }
        }
#pragma unroll
        for (int ksub = 0; ksub < 2; ++ksub)
#pragma unroll
            for (int m = 0; m < 4; ++m)
#pragma unroll
                for (int n = 0; n < 4; ++n)
                    acc[m][n] = __builtin_amdgcn_mfma_f32_16x16x32_bf16(
                        af[m][ksub], bf[n][ksub], acc[m][n], 0, 0, 0);
        __syncthreads();
    }

    if (expmode) {
#pragma unroll
        for (int m = 0; m < 4; ++m) {
            f32x4 rs = (f32x4){0.f, 0.f, 0.f, 0.f};
#pragma unroll
            for (int n = 0; n < 4; ++n) {
                const int cls = col0 + wc * 64 + n * 16 + (lane & 15);
                if (cls < HEAD_N) {
#pragma unroll
                    for (int r = 0; r < 4; ++r) rs[r] += __expf(acc[m][n][r]);
                }
            }
#pragma unroll
            for (int msk = 1; msk < 16; msk <<= 1) {
#pragma unroll
                for (int r = 0; r < 4; ++r) rs[r] += __shfl_xor(rs[r], msk, 64);
            }
            if ((lane & 15) == 0) {
                const int rb = row0 + wr * 64 + m * 16 + (lane >> 4) * 4;
#pragma unroll
                for (int r = 0; r < 4; ++r) atomicAdd(&SEH[rb + r], rs[r]);
            }
        }
    } else {
        const int pc0 = col0 - HEAD_NP;
#pragma unroll
        for (int m = 0; m < 4; ++m) {
#pragma unroll
            for (int n = 0; n < 4; ++n) {
                const int col = pc0 + wc * 64 + n * 16 + (lane & 15);
                if (col < PCAT) {
#pragma unroll
                    for (int r = 0; r < 4; ++r) {
                        const int row = row0 + wr * 64 + m * 16 + (lane >> 4) * 4 + r;
                        const float v = acc[m][n][r];
                        HF[(size_t)row * PCAT + col] = v;
                        HB[(size_t)row * PCAT + col] = f32_to_bf16(v);
                    }
                }
            }
        }
    }
}

// ---------------- streaming sum-exp: rows in registers, W streamed ----------------
// Block = 4 waves x 32 rows = 128 rows. A-frags live in VGPRs for the whole
// kernel. Col-tiles of W [CT x K] double-buffered through LDS (XOR-swizzled,
// staged by global_load_lds with pre-swizzled source). exp-sums accumulate in
// registers across all tiles; one shuffle-reduce + atomicAdd set per block.
template<int K, int CT>
__launch_bounds__(256, 2)
__global__ void sumexp_stream(const u16* __restrict__ H, int ldh,
                              const u16* __restrict__ W,
                              int nreal, int tps, int ntiles,
                              float* __restrict__ SE)
{
    constexpr int MSETS = 2;            // 16-row sets per wave
    constexpr int NKF   = K / 32;       // K fragments
    constexpr int SLOTS = K / 8;        // 16B slots per W row
    constexpr int NT    = CT / 16;      // col fragments per tile
    constexpr int CHUNKS = CT * K * 2 / 4096;  // 4KB staging rounds
    constexpr int RPC   = 256 / SLOTS;  // W rows per 4KB chunk
    __shared__ u16 ldsB[2][CT * K];

    const int tid  = threadIdx.x;
    const int wid  = tid >> 6;
    const int lane = tid & 63;
    const int row0 = blockIdx.x * (4 * MSETS * 16) + wid * (MSETS * 16);

    // A fragments: rows resident in registers
    bf16x8 afr[MSETS][NKF];
#pragma unroll
    for (int m = 0; m < MSETS; ++m) {
        const u16* hr = H + (size_t)(row0 + m * 16 + (lane & 15)) * ldh + (lane >> 4) * 8;
#pragma unroll
        for (int kf = 0; kf < NKF; ++kf)
            afr[m][kf] = *(const bf16x8*)(hr + kf * 32);
    }

    float rs[MSETS][4];
#pragma unroll
    for (int m = 0; m < MSETS; ++m)
#pragma unroll
        for (int r = 0; r < 4; ++r) rs[m][r] = 0.f;

    // staging geometry (chunk-invariant per thread)
    const int trow   = tid / SLOTS;               // row within chunk
    const int swoff  = ((tid % SLOTS) ^ (trow & 7)) * 8;  // swizzled elem offset in row
    const int t0 = blockIdx.y * tps;
    const int t1 = min(t0 + tps, ntiles);

    auto STAGE = [&](int t, int buf) {
        const u16* wb = W + (size_t)t * CT * K + (size_t)trow * K + swoff;
        u16* lb = &ldsB[buf][wid * 512];
#pragma unroll
        for (int c = 0; c < CHUNKS; ++c)
            gload_lds16(wb + (size_t)c * RPC * K, lb + c * 2048);
    };

    int cur = 0;
    STAGE(t0, 0);
    __syncthreads();

    for (int t = t0; t < t1; ++t) {
        if (t + 1 < t1) STAGE(t + 1, cur ^ 1);

        const bf16x8* B8 = (const bf16x8*)ldsB[cur];
        const bool full = (t + 1) * CT <= nreal;
#pragma unroll
        for (int n = 0; n < NT; ++n) {
            const int br = n * 16 + (lane & 15);
            bf16x8 bfr[NKF];
#pragma unroll
            for (int kf = 0; kf < NKF; ++kf)
                bfr[kf] = B8[br * SLOTS + ((kf * 4 + (lane >> 4)) ^ (br & 7))];
            f32x4 acc[MSETS];
#pragma unroll
            for (int m = 0; m < MSETS; ++m) acc[m] = (f32x4){0.f, 0.f, 0.f, 0.f};
#pragma unroll
            for (int m = 0; m < MSETS; ++m)
#pragma unroll
                for (int kf = 0; kf < NKF; ++kf)
                    acc[m] = __builtin_amdgcn_mfma_f32_16x16x32_bf16(
                        afr[m][kf], bfr[kf], acc[m], 0, 0, 0);
            if (full) {
#pragma unroll
                for (int m = 0; m < MSETS; ++m)
#pragma unroll
                    for (int r = 0; r < 4; ++r) rs[m][r] += __expf(acc[m][r]);
            } else {
                const int cls = t * CT + n * 16 + (lane & 15);
                if (cls < nreal) {
#pragma unroll
                    for (int m = 0; m < MSETS; ++m)
#pragma unroll
                        for (int r = 0; r < 4; ++r) rs[m][r] += __expf(acc[m][r]);
                }
            }
        }
        __syncthreads();   // drains prefetch vmcnt(0) + makes buf swap safe
        cur ^= 1;
    }

    // one reduction + atomic set per block
#pragma unroll
    for (int msk = 1; msk < 16; msk <<= 1)
#pragma unroll
        for (int m = 0; m < MSETS; ++m)
#pragma unroll
            for (int r = 0; r < 4; ++r)
                rs[m][r] += __shfl_xor(rs[m][r], msk, 64);
    if ((lane & 15) == 0) {
        const int rb = row0 + (lane >> 4) * 4;
#pragma unroll
        for (int m = 0; m < MSETS; ++m)
#pragma unroll
            for (int r = 0; r < 4; ++r)
                atomicAdd(&SE[rb + m * 16 + r], rs[m][r]);
    }
}

// ---------------- per-row epilogue: target dots (fp32) + combine ----------------
__global__ void epilogue_kernel(const float* __restrict__ x, const int* __restrict__ tgt,
                                const float* __restrict__ head_w,
                                const float* __restrict__ out0, const float* __restrict__ out1,
                                const float* __restrict__ hcatf,
                                const float* __restrict__ se_head, const float* __restrict__ se_c0,
                                const float* __restrict__ se_c1,
                                float* __restrict__ rowlogp, float* __restrict__ rowvalid) {
    const int r = blockIdx.x;
    const int tid = threadIdx.x;
    const int t = tgt[r];
    const bool valid = (t != IGNORE);
    const int tc = valid ? t : 0;
    const int band = (tc < C0_LO) ? 0 : (tc < C0_HI) ? 1 : 2;
    const int headclass = (band == 0) ? tc : (C0_LO + band - 1);

    const float* xr = x + (size_t)r * INF;
    const float* wr = head_w + (size_t)headclass * INF;
    float p1 = 0.f;
    for (int k = tid; k < INF; k += 256) p1 += xr[k] * wr[k];

    float p2 = 0.f;
    if (band == 1) {
        const float* hr = hcatf + (size_t)r * PCAT;
        const float* cr = out0 + (size_t)(tc - C0_LO) * K0;
        for (int k = tid; k < K0; k += 256) p2 += hr[k] * cr[k];
    } else if (band == 2) {
        const float* hr = hcatf + (size_t)r * PCAT + 256;
        const float* cr = out1 + (size_t)(tc - C0_HI) * K1;
        for (int k = tid; k < K1; k += 256) p2 += hr[k] * cr[k];
    }

    __shared__ float s1[256], s2[256];
    s1[tid] = p1; s2[tid] = p2;
    __syncthreads();
    for (int s = 128; s > 0; s >>= 1) {
        if (tid < s) { s1[tid] += s1[tid + s]; s2[tid] += s2[tid + s]; }
        __syncthreads();
    }
    if (tid == 0) {
        float logp = s1[0] - __logf(se_head[r]);
        if (band == 1)      logp += s2[0] - __logf(se_c0[r]);
        else if (band == 2) logp += s2[0] - __logf(se_c1[r]);
        rowlogp[r]  = valid ? logp : 0.f;
        rowvalid[r] = valid ? 1.f : 0.f;
    }
}

// ---------------- deterministic final reduce ----------------
__global__ void final_reduce(const float* __restrict__ rowlogp,
                             const float* __restrict__ rowvalid, float* __restrict__ out) {
    __shared__ float sl[256], sv[256];
    const int tid = threadIdx.x;
    float a = 0.f, b = 0.f;
    for (int i = tid; i < NR; i += 256) { a += rowlogp[i]; b += rowvalid[i]; }
    sl[tid] = a; sv[tid] = b;
    __syncthreads();
    for (int s = 128; s > 0; s >>= 1) {
        if (tid < s) { sl[tid] += sl[tid + s]; sv[tid] += sv[tid + s]; }
        __syncthreads();
    }
    if (tid == 0) out[0] = -sl[0] / sv[0];
}

extern "C" void kernel_launch(void* const* d_in, const int* in_sizes, int n_in,
                              void* d_out, int out_size, void* d_ws, size_t ws_size,
                              hipStream_t stream) {
    const float* x      = (const float*)d_in[0];
    const int*   tgt    = (const int*)d_in[1];
    const float* head_w = (const float*)d_in[2];
    const float* proj0  = (const float*)d_in[3];
    const float* out0   = (const float*)d_in[4];
    const float* proj1  = (const float*)d_in[5];
    const float* out1   = (const float*)d_in[6];
    float* loss = (float*)d_out;

    char* base = (char*)d_ws;
    size_t off = 0;
    auto alloc = [&](size_t bytes) { char* p = base + off; off += (bytes + 255) & ~(size_t)255; return p; };

    u16* xb    = (u16*)alloc((size_t)NR * INF * 2);
    u16* wcatb = (u16*)alloc((size_t)WCAT_R * INF * 2);
    u16* o0b   = (u16*)alloc((size_t)C0_NP * K0 * 2);
    u16* o1b   = (u16*)alloc((size_t)C1_NP * K1 * 2);
    float* hcatf = (float*)alloc((size_t)NR * PCAT * 4);
    u16*   hcatb = (u16*)alloc((size_t)NR * PCAT * 2);
    float* se_head = (float*)alloc((size_t)NR * 4);
    float* se_c0   = (float*)alloc((size_t)NR * 4);
    float* se_c1   = (float*)alloc((size_t)NR * 4);
    float* rowlogp  = (float*)alloc((size_t)NR * 4);
    float* rowvalid = (float*)alloc((size_t)NR * 4);

    hipMemsetAsync(se_head, 0, (size_t)NR * 4, stream);
    hipMemsetAsync(se_c0,   0, (size_t)NR * 4, stream);
    hipMemsetAsync(se_c1,   0, (size_t)NR * 4, stream);

    CvtSegs segs;
    segs.s[0] = x;      segs.d[0] = xb;                              segs.n8[0] = NR * INF / 8;
    segs.s[1] = head_w; segs.d[1] = wcatb;                           segs.n8[1] = HEAD_N * INF / 8;
    segs.s[2] = proj0;  segs.d[2] = wcatb + (size_t)HEAD_NP * INF;   segs.n8[2] = 256 * INF / 8;
    segs.s[3] = proj1;  segs.d[3] = wcatb + (size_t)(HEAD_NP + 256) * INF; segs.n8[3] = 64 * INF / 8;
    segs.s[4] = out0;   segs.d[4] = o0b;                             segs.n8[4] = C0_N * K0 / 8;
    segs.s[5] = out1;   segs.d[5] = o1b;                             segs.n8[5] = C1_N * K1 / 8;
    cvt_multi<<<2048, 256, 0, stream>>>(segs);

    // head sum-exp (cols 0..2047) + proj store (cols 2048..2431) in one dispatch
    fused_headproj<<<dim3(32, (HEAD_NP + PCAT_P) / 128), 256, 0, stream>>>(
        xb, wcatb, se_head, hcatf, hcatb);

    // cluster sum-exps: rows-in-registers streaming kernels
    // C0: K=256, CT=64, 125 real tiles, 16 splits x 8
    sumexp_stream<K0, 64><<<dim3(32, 16), 256, 0, stream>>>(
        hcatb, PCAT, o0b, C0_N, 8, 125, se_c0);
    // C1: K=64, CT=128, 315 tiles, 16 splits x 20
    sumexp_stream<K1, 128><<<dim3(32, 16), 256, 0, stream>>>(
        hcatb + 256, PCAT, o1b, C1_N, 20, 315, se_c1);

    epilogue_kernel<<<NR, 256, 0, stream>>>(x, tgt, head_w, out0, out1, hcatf,
                                            se_head, se_c0, se_c1, rowlogp, rowvalid);
    final_reduce<<<1, 256, 0, stream>>>(rowlogp, rowvalid, loss);
    (void)in_sizes; (void)n_in; (void)out_size; (void)ws_size;
}

// Round 4
// 109.839 us; speedup vs baseline: 4.3231x; 1.0618x over previous
//
#include <hip/hip_runtime.h>
#include <hip/hip_bf16.h>

typedef __attribute__((ext_vector_type(8))) short bf16x8;
typedef __attribute__((ext_vector_type(4))) float f32x4;
typedef unsigned short u16;

// Problem constants
constexpr int NR      = 4096;
constexpr int INF     = 1024;
constexpr int HEAD_N  = 2002;
constexpr int HEAD_NP = 2048;     // 16 col-tiles of 128
constexpr int C0_LO   = 2000, C0_HI = 10000;
constexpr int C0_N    = 8000;
constexpr int C0_NP   = 8064;
constexpr int C1_N    = 40257;
constexpr int C1_NP   = 40320;
constexpr int K0      = 256;
constexpr int K1      = 64;
constexpr int PCAT    = 320;      // 256 + 64 concatenated proj rows
constexpr int PCAT_P  = 384;      // 3 col-tiles of 128
constexpr int WCAT_R  = HEAD_NP + PCAT_P;  // 2432 rows in merged B
constexpr int IGNORE  = -1;
constexpr float LOG2E = 1.4426950408889634f;
constexpr float LN2   = 0.6931471805599453f;

static __device__ __forceinline__ u16 f32_to_bf16(float f) {
    unsigned int u = __float_as_uint(f);
    return (u16)((u + 0x7FFFu + ((u >> 16) & 1u)) >> 16);
}

static __device__ __forceinline__ float fast_exp2(float x) {
#if __has_builtin(__builtin_amdgcn_exp2f)
    return __builtin_amdgcn_exp2f(x);           // raw v_exp_f32
#else
    return __expf(x * LN2);                     // fallback keeps the mul
#endif
}

static __device__ __forceinline__ void gload_lds16(const u16* g, u16* l) {
    __builtin_amdgcn_global_load_lds(
        (const __attribute__((address_space(1))) unsigned int*)g,
        (__attribute__((address_space(3))) unsigned int*)l, 16, 0, 0);
}

// ---------------- fused multi-segment fp32 -> bf16 convert (with scale) ----------------
struct CvtSegs { const float* s[6]; u16* d[6]; int n8[6]; float sc[6]; };

__global__ void cvt_multi(CvtSegs segs) {
    const int stride = gridDim.x * blockDim.x;
    const int gid = blockIdx.x * blockDim.x + threadIdx.x;
#pragma unroll
    for (int seg = 0; seg < 6; ++seg) {
        const float4* sp = (const float4*)segs.s[seg];
        bf16x8* dp = (bf16x8*)segs.d[seg];
        const int n8 = segs.n8[seg];
        const float sc = segs.sc[seg];
        for (int i = gid; i < n8; i += stride) {
            float4 a = sp[2 * i], b = sp[2 * i + 1];
            bf16x8 o;
            o[0] = (short)f32_to_bf16(a.x * sc); o[1] = (short)f32_to_bf16(a.y * sc);
            o[2] = (short)f32_to_bf16(a.z * sc); o[3] = (short)f32_to_bf16(a.w * sc);
            o[4] = (short)f32_to_bf16(b.x * sc); o[5] = (short)f32_to_bf16(b.y * sc);
            o[6] = (short)f32_to_bf16(b.z * sc); o[7] = (short)f32_to_bf16(b.w * sc);
            dp[i] = o;
        }
    }
}

// ---------------- merged head+proj 128x128 tile GEMM (K=1024) ----------------
// blockIdx.y < 16 : head col-tile -> exp2-sum into SEH + capture target logit
// blockIdx.y >= 16: proj col-tile -> store f32+bf16 into hcat
// head_w is pre-scaled by log2(e): logits come out scaled; sum uses exp2.
__launch_bounds__(256, 2)
__global__ void fused_headproj(const u16* __restrict__ A, const u16* __restrict__ B,
                               const int* __restrict__ tgt,
                               float* __restrict__ SEH, float* __restrict__ TL,
                               float* __restrict__ HF, u16* __restrict__ HB)
{
    constexpr int K = INF;
    __shared__ u16 ldsA[128 * 64];
    __shared__ u16 ldsB[128 * 64];
    __shared__ int sth[128];
    const int tid  = threadIdx.x;
    const int wid  = tid >> 6;
    const int lane = tid & 63;
    const int wr   = wid >> 1;
    const int wc   = wid & 1;
    const int row0 = blockIdx.x * 128;
    const int col0 = blockIdx.y * 128;
    const bool expmode = (blockIdx.y < HEAD_NP / 128);

    if (expmode && tid < 128) {
        int t = tgt[row0 + tid];
        sth[tid] = (t < 0) ? 0 : (t < C0_LO ? t : (t < C0_HI ? C0_LO : C0_LO + 1));
    }

    f32x4 acc[4][4];
#pragma unroll
    for (int m = 0; m < 4; ++m)
#pragma unroll
        for (int n = 0; n < 4; ++n) acc[m][n] = (f32x4){0.f, 0.f, 0.f, 0.f};

    const int srow = lane >> 3;
    const int ssw  = (lane & 7) ^ srow;

    for (int ks = 0; ks < K / 64; ++ks) {
        const int k0 = ks * 64;
#pragma unroll
        for (int q = 0; q < 4; ++q) {
            const int c   = q * 4 + wid;
            const int row = c * 8 + srow;
            gload_lds16(A + (size_t)(row0 + row) * K + k0 + ssw * 8, ldsA + c * 512);
        }
#pragma unroll
        for (int q = 0; q < 4; ++q) {
            const int c   = q * 4 + wid;
            const int row = c * 8 + srow;
            gload_lds16(B + (size_t)(col0 + row) * K + k0 + ssw * 8, ldsB + c * 512);
        }
        __syncthreads();

        const bf16x8* A8 = (const bf16x8*)ldsA;
        const bf16x8* B8 = (const bf16x8*)ldsB;
        bf16x8 af[4][2], bf[4][2];
#pragma unroll
        for (int m = 0; m < 4; ++m) {
            const int ar = wr * 64 + m * 16 + (lane & 15);
#pragma unroll
            for (int ksub = 0; ksub < 2; ++ksub) {
                const int slot = ksub * 4 + (lane >> 4);
                af[m][ksub] = A8[ar * 8 + (slot ^ (ar & 7))];
            }
        }
#pragma unroll
        for (int n = 0; n < 4; ++n) {
            const int br = wc * 64 + n * 16 + (lane & 15);
#pragma unroll
            for (int ksub = 0; ksub < 2; ++ksub) {
                const int slot = ksub * 4 + (lane >> 4);
                bf[n][ksub] = B8[br * 8 + (slot ^ (br & 7))];
            }
        }
#pragma unroll
        for (int ksub = 0; ksub < 2; ++ksub)
#pragma unroll
            for (int m = 0; m < 4; ++m)
#pragma unroll
                for (int n = 0; n < 4; ++n)
                    acc[m][n] = __builtin_amdgcn_mfma_f32_16x16x32_bf16(
                        af[m][ksub], bf[n][ksub], acc[m][n], 0, 0, 0);
        __syncthreads();
    }

    if (expmode) {
#pragma unroll
        for (int m = 0; m < 4; ++m) {
            f32x4 rs = (f32x4){0.f, 0.f, 0.f, 0.f};
#pragma unroll
            for (int n = 0; n < 4; ++n) {
                const int cls = col0 + wc * 64 + n * 16 + (lane & 15);
                if (cls < HEAD_N) {
#pragma unroll
                    for (int r = 0; r < 4; ++r) {
                        rs[r] += fast_exp2(acc[m][n][r]);
                        const int lrow = wr * 64 + m * 16 + (lane >> 4) * 4 + r;
                        if (sth[lrow] == cls) TL[row0 + lrow] = acc[m][n][r];
                    }
                }
            }
#pragma unroll
            for (int msk = 1; msk < 16; msk <<= 1) {
#pragma unroll
                for (int r = 0; r < 4; ++r) rs[r] += __shfl_xor(rs[r], msk, 64);
            }
            if ((lane & 15) == 0) {
                const int rb = row0 + wr * 64 + m * 16 + (lane >> 4) * 4;
#pragma unroll
                for (int r = 0; r < 4; ++r) atomicAdd(&SEH[rb + r], rs[r]);
            }
        }
    } else {
        const int pc0 = col0 - HEAD_NP;
#pragma unroll
        for (int m = 0; m < 4; ++m) {
#pragma unroll
            for (int n = 0; n < 4; ++n) {
                const int col = pc0 + wc * 64 + n * 16 + (lane & 15);
                if (col < PCAT) {
#pragma unroll
                    for (int r = 0; r < 4; ++r) {
                        const int row = row0 + wr * 64 + m * 16 + (lane >> 4) * 4 + r;
                        const float v = acc[m][n][r];
                        HF[(size_t)row * PCAT + col] = v;
                        HB[(size_t)row * PCAT + col] = f32_to_bf16(v);
                    }
                }
            }
        }
    }
}

// ---------------- streaming sum-exp: rows in registers, W streamed ----------------
// Block = 4 waves x 32 rows = 128 rows. W pre-scaled by log2(e) -> exp2.
template<int K, int CT>
__launch_bounds__(256, 2)
__global__ void sumexp_stream(const u16* __restrict__ H, int ldh,
                              const u16* __restrict__ W,
                              int nreal, int tps, int ntiles,
                              float* __restrict__ SE)
{
    constexpr int MSETS = 2;
    constexpr int NKF   = K / 32;
    constexpr int SLOTS = K / 8;
    constexpr int NT    = CT / 16;
    constexpr int CHUNKS = CT * K * 2 / 4096;
    constexpr int RPC   = 256 / SLOTS;
    __shared__ u16 ldsB[2][CT * K];

    const int tid  = threadIdx.x;
    const int wid  = tid >> 6;
    const int lane = tid & 63;
    const int row0 = blockIdx.x * (4 * MSETS * 16) + wid * (MSETS * 16);

    const int t0 = blockIdx.y * tps;
    const int t1 = min(t0 + tps, ntiles);
    if (t0 >= t1) return;

    bf16x8 afr[MSETS][NKF];
#pragma unroll
    for (int m = 0; m < MSETS; ++m) {
        const u16* hr = H + (size_t)(row0 + m * 16 + (lane & 15)) * ldh + (lane >> 4) * 8;
#pragma unroll
        for (int kf = 0; kf < NKF; ++kf)
            afr[m][kf] = *(const bf16x8*)(hr + kf * 32);
    }

    float rs[MSETS][4];
#pragma unroll
    for (int m = 0; m < MSETS; ++m)
#pragma unroll
        for (int r = 0; r < 4; ++r) rs[m][r] = 0.f;

    const int trow   = tid / SLOTS;
    const int swoff  = ((tid % SLOTS) ^ (trow & 7)) * 8;

    auto STAGE = [&](int t, int buf) {
        const u16* wb = W + (size_t)t * CT * K + (size_t)trow * K + swoff;
        u16* lb = &ldsB[buf][wid * 512];
#pragma unroll
        for (int c = 0; c < CHUNKS; ++c)
            gload_lds16(wb + (size_t)c * RPC * K, lb + c * 2048);
    };

    int cur = 0;
    STAGE(t0, 0);
    __syncthreads();

    for (int t = t0; t < t1; ++t) {
        if (t + 1 < t1) STAGE(t + 1, cur ^ 1);

        const bf16x8* B8 = (const bf16x8*)ldsB[cur];
        const bool full = (t + 1) * CT <= nreal;
#pragma unroll
        for (int n = 0; n < NT; ++n) {
            const int br = n * 16 + (lane & 15);
            bf16x8 bfr[NKF];
#pragma unroll
            for (int kf = 0; kf < NKF; ++kf)
                bfr[kf] = B8[br * SLOTS + ((kf * 4 + (lane >> 4)) ^ (br & 7))];
            f32x4 acc[MSETS];
#pragma unroll
            for (int m = 0; m < MSETS; ++m) acc[m] = (f32x4){0.f, 0.f, 0.f, 0.f};
#pragma unroll
            for (int m = 0; m < MSETS; ++m)
#pragma unroll
                for (int kf = 0; kf < NKF; ++kf)
                    acc[m] = __builtin_amdgcn_mfma_f32_16x16x32_bf16(
                        afr[m][kf], bfr[kf], acc[m], 0, 0, 0);
            if (full) {
#pragma unroll
                for (int m = 0; m < MSETS; ++m)
#pragma unroll
                    for (int r = 0; r < 4; ++r) rs[m][r] += fast_exp2(acc[m][r]);
            } else {
                const int cls = t * CT + n * 16 + (lane & 15);
                if (cls < nreal) {
#pragma unroll
                    for (int m = 0; m < MSETS; ++m)
#pragma unroll
                        for (int r = 0; r < 4; ++r) rs[m][r] += fast_exp2(acc[m][r]);
                }
            }
        }
        __syncthreads();
        cur ^= 1;
    }

#pragma unroll
    for (int msk = 1; msk < 16; msk <<= 1)
#pragma unroll
        for (int m = 0; m < MSETS; ++m)
#pragma unroll
            for (int r = 0; r < 4; ++r)
                rs[m][r] += __shfl_xor(rs[m][r], msk, 64);
    if ((lane & 15) == 0) {
        const int rb = row0 + (lane >> 4) * 4;
#pragma unroll
        for (int m = 0; m < MSETS; ++m)
#pragma unroll
            for (int r = 0; r < 4; ++r)
                atomicAdd(&SE[rb + m * 16 + r], rs[m][r]);
    }
}

// ---------------- per-row epilogue: one wave per row ----------------
__global__ void epilogue_kernel(const int* __restrict__ tgt, const float* __restrict__ tl,
                                const float* __restrict__ out0, const float* __restrict__ out1,
                                const float* __restrict__ hcatf,
                                const float* __restrict__ se_head, const float* __restrict__ se_c0,
                                const float* __restrict__ se_c1,
                                float* __restrict__ rowlogp, float* __restrict__ rowvalid) {
    const int wid = threadIdx.x >> 6, lane = threadIdx.x & 63;
    const int r = blockIdx.x * 4 + wid;
    const int t = tgt[r];
    const bool valid = (t != IGNORE);
    const int tc = valid ? t : 0;
    const int band = (tc < C0_LO) ? 0 : (tc < C0_HI) ? 1 : 2;

    float p2 = 0.f;
    if (band == 1) {
        const float* hr = hcatf + (size_t)r * PCAT;
        const float* cr = out0 + (size_t)(tc - C0_LO) * K0;
        for (int k = lane; k < K0; k += 64) p2 += hr[k] * cr[k];
    } else if (band == 2) {
        p2 = hcatf[(size_t)r * PCAT + 256 + lane] * out1[(size_t)(tc - C0_HI) * K1 + lane];
    }
#pragma unroll
    for (int msk = 32; msk >= 1; msk >>= 1) p2 += __shfl_xor(p2, msk, 64);

    if (lane == 0) {
        float logp = LN2 * tl[r] - __logf(se_head[r]);   // captured logit is log2e-scaled
        if (band == 1)      logp += p2 - __logf(se_c0[r]);
        else if (band == 2) logp += p2 - __logf(se_c1[r]);
        rowlogp[r]  = valid ? logp : 0.f;
        rowvalid[r] = valid ? 1.f : 0.f;
    }
}

// ---------------- deterministic final reduce ----------------
__global__ void final_reduce(const float* __restrict__ rowlogp,
                             const float* __restrict__ rowvalid, float* __restrict__ out) {
    __shared__ float sl[256], sv[256];
    const int tid = threadIdx.x;
    float a = 0.f, b = 0.f;
    for (int i = tid; i < NR; i += 256) { a += rowlogp[i]; b += rowvalid[i]; }
    sl[tid] = a; sv[tid] = b;
    __syncthreads();
    for (int s = 128; s > 0; s >>= 1) {
        if (tid < s) { sl[tid] += sl[tid + s]; sv[tid] += sv[tid + s]; }
        __syncthreads();
    }
    if (tid == 0) out[0] = -sl[0] / sv[0];
}

extern "C" void kernel_launch(void* const* d_in, const int* in_sizes, int n_in,
                              void* d_out, int out_size, void* d_ws, size_t ws_size,
                              hipStream_t stream) {
    const float* x      = (const float*)d_in[0];
    const int*   tgt    = (const int*)d_in[1];
    const float* head_w = (const float*)d_in[2];
    const float* proj0  = (const float*)d_in[3];
    const float* out0   = (const float*)d_in[4];
    const float* proj1  = (const float*)d_in[5];
    const float* out1   = (const float*)d_in[6];
    float* loss = (float*)d_out;

    char* base = (char*)d_ws;
    size_t off = 0;
    auto alloc = [&](size_t bytes) { char* p = base + off; off += (bytes + 255) & ~(size_t)255; return p; };

    u16* xb    = (u16*)alloc((size_t)NR * INF * 2);
    u16* wcatb = (u16*)alloc((size_t)WCAT_R * INF * 2);
    u16* o0b   = (u16*)alloc((size_t)C0_NP * K0 * 2);
    u16* o1b   = (u16*)alloc((size_t)C1_NP * K1 * 2);
    float* hcatf = (float*)alloc((size_t)NR * PCAT * 4);
    u16*   hcatb = (u16*)alloc((size_t)NR * PCAT * 2);
    float* se_head = (float*)alloc((size_t)NR * 4);
    float* se_c0   = (float*)alloc((size_t)NR * 4);
    float* se_c1   = (float*)alloc((size_t)NR * 4);
    float* tl       = (float*)alloc((size_t)NR * 4);
    float* rowlogp  = (float*)alloc((size_t)NR * 4);
    float* rowvalid = (float*)alloc((size_t)NR * 4);

    hipMemsetAsync(se_head, 0, (size_t)NR * 4, stream);
    hipMemsetAsync(se_c0,   0, (size_t)NR * 4, stream);
    hipMemsetAsync(se_c1,   0, (size_t)NR * 4, stream);

    CvtSegs segs;
    segs.s[0] = x;      segs.d[0] = xb;                              segs.n8[0] = NR * INF / 8;      segs.sc[0] = 1.0f;
    segs.s[1] = head_w; segs.d[1] = wcatb;                           segs.n8[1] = HEAD_N * INF / 8;  segs.sc[1] = LOG2E;
    segs.s[2] = proj0;  segs.d[2] = wcatb + (size_t)HEAD_NP * INF;   segs.n8[2] = 256 * INF / 8;     segs.sc[2] = 1.0f;
    segs.s[3] = proj1;  segs.d[3] = wcatb + (size_t)(HEAD_NP + 256) * INF; segs.n8[3] = 64 * INF / 8; segs.sc[3] = 1.0f;
    segs.s[4] = out0;   segs.d[4] = o0b;                             segs.n8[4] = C0_N * K0 / 8;     segs.sc[4] = LOG2E;
    segs.s[5] = out1;   segs.d[5] = o1b;                             segs.n8[5] = C1_N * K1 / 8;     segs.sc[5] = LOG2E;
    cvt_multi<<<2048, 256, 0, stream>>>(segs);

    // head sum-exp + target-logit capture (cols 0..2047) + proj store (2048..2431)
    fused_headproj<<<dim3(32, WCAT_R / 128), 256, 0, stream>>>(
        xb, wcatb, tgt, se_head, tl, hcatf, hcatb);

    // cluster sum-exps: rows-in-registers streaming kernels
    // C0: K=256, CT=32, 250 tiles, 32 splits x 8  -> 1024 blocks (4/CU, 32KB LDS)
    sumexp_stream<K0, 32><<<dim3(32, 32), 256, 0, stream>>>(
        hcatb, PCAT, o0b, C0_N, 8, 250, se_c0);
    // C1: K=64, CT=128, 315 tiles, 40 splits x 8  -> 1280 blocks (5/CU, 32KB LDS)
    sumexp_stream<K1, 128><<<dim3(32, 40), 256, 0, stream>>>(
        hcatb + 256, PCAT, o1b, C1_N, 8, 315, se_c1);

    epilogue_kernel<<<NR / 4, 256, 0, stream>>>(tgt, tl, out0, out1, hcatf,
                                                se_head, se_c0, se_c1, rowlogp, rowvalid);
    final_reduce<<<1, 256, 0, stream>>>(rowlogp, rowvalid, loss);
    (void)in_sizes; (void)n_in; (void)out_size; (void)ws_size;
}

// Round 6
// 100.486 us; speedup vs baseline: 4.7255x; 1.0931x over previous
//
#include <hip/hip_runtime.h>
#include <hip/hip_bf16.h>

typedef __attribute__((ext_vector_type(8))) short bf16x8;
typedef __attribute__((ext_vector_type(4))) float f32x4;
typedef unsigned short u16;

// Problem constants
constexpr int NR      = 4096;
constexpr int INF     = 1024;
constexpr int HEAD_N  = 2002;
constexpr int HEAD_NP = 2048;     // 16 col-tiles of 128
constexpr int C0_LO   = 2000, C0_HI = 10000;
constexpr int C0_N    = 8000;
constexpr int C1_N    = 40257;
constexpr int C1_NP   = 40320;
constexpr int K0      = 256;
constexpr int K1      = 64;
constexpr int PCAT    = 320;      // 256 + 64 concatenated proj rows
constexpr int PCAT_P  = 384;      // 3 col-tiles of 128
constexpr int WCAT_R  = HEAD_NP + PCAT_P;  // 2432 rows in merged B
constexpr int IGNORE  = -1;
constexpr float LOG2E = 1.4426950408889634f;
constexpr float LN2   = 0.6931471805599453f;

// mega-kernel geometry
constexpr int S0      = 16;       // C0 split-K count  (tps = 16 over 250 tiles)
constexpr int S1      = 10;       // C1 split-K count  (tps = 32 over 315 tiles)
constexpr int NHP     = 32;       // head partial slots: 16 col-tiles x 2 wc halves
constexpr int MEGA_GRID = 1024 + 512;   // [0,1024): even=head, odd=C1; [1024,1536): C0

static __device__ __forceinline__ u16 f32_to_bf16(float f) {
    unsigned int u = __float_as_uint(f);
    return (u16)((u + 0x7FFFu + ((u >> 16) & 1u)) >> 16);
}

static __device__ __forceinline__ float fast_exp2(float x) {
#if __has_builtin(__builtin_amdgcn_exp2f)
    return __builtin_amdgcn_exp2f(x);
#else
    return __expf(x * LN2);
#endif
}

static __device__ __forceinline__ void gload_lds16(const u16* g, u16* l) {
    __builtin_amdgcn_global_load_lds(
        (const __attribute__((address_space(1))) unsigned int*)g,
        (__attribute__((address_space(3))) unsigned int*)l, 16, 0, 0);
}

// ---------------- fused multi-segment fp32 -> bf16 convert (with scale) ----------------
struct CvtSegs { const float* s[6]; u16* d[6]; int n8[6]; float sc[6]; };

__global__ void cvt_multi(CvtSegs segs) {
    const int stride = gridDim.x * blockDim.x;
    const int gid = blockIdx.x * blockDim.x + threadIdx.x;
#pragma unroll
    for (int seg = 0; seg < 6; ++seg) {
        const float4* sp = (const float4*)segs.s[seg];
        bf16x8* dp = (bf16x8*)segs.d[seg];
        const int n8 = segs.n8[seg];
        const float sc = segs.sc[seg];
        for (int i = gid; i < n8; i += stride) {
            float4 a = sp[2 * i], b = sp[2 * i + 1];
            bf16x8 o;
            o[0] = (short)f32_to_bf16(a.x * sc); o[1] = (short)f32_to_bf16(a.y * sc);
            o[2] = (short)f32_to_bf16(a.z * sc); o[3] = (short)f32_to_bf16(a.w * sc);
            o[4] = (short)f32_to_bf16(b.x * sc); o[5] = (short)f32_to_bf16(b.y * sc);
            o[6] = (short)f32_to_bf16(b.z * sc); o[7] = (short)f32_to_bf16(b.w * sc);
            dp[i] = o;
        }
    }
}

// ---------------- band compaction: per-cluster row lists ----------------
// one block of 1024 threads; slot order is atomic-nondeterministic but every
// per-row value downstream is slot-independent -> loss is replay-identical.
__global__ void compact_kernel(const int* __restrict__ tgt,
                               int* __restrict__ c0list, int* __restrict__ c1list,
                               int* __restrict__ crow, int* __restrict__ cnts) {
    __shared__ int b0, b1;
    if (threadIdx.x == 0) { b0 = 0; b1 = 0; }
    __syncthreads();
#pragma unroll
    for (int i = 0; i < 4; ++i) {
        const int r = threadIdx.x + i * 1024;
        const int t = tgt[r];
        if (t >= C0_LO && t < C0_HI) { int s = atomicAdd(&b0, 1); c0list[s] = r; crow[r] = s; }
        else if (t >= C0_HI)         { int s = atomicAdd(&b1, 1); c1list[s] = r; crow[r] = s; }
        else crow[r] = 0;
    }
    __syncthreads();
    const int c0 = b0, c1 = b1;
    const int p0 = (c0 + 127) & ~127, p1 = (c1 + 127) & ~127;
    if (threadIdx.x == 0) { cnts[0] = c0; cnts[1] = c1; cnts[2] = p0; cnts[3] = p1; }
    for (int i = c0 + (int)threadIdx.x; i < p0; i += 1024) c0list[i] = 0;
    for (int i = c1 + (int)threadIdx.x; i < p1; i += 1024) c1list[i] = 0;
}

// ---------------- proj GEMM: hcat = X @ [proj0;proj1]^T ----------------
__launch_bounds__(256, 2)
__global__ void proj_tile(const u16* __restrict__ A, const u16* __restrict__ B,
                          float* __restrict__ HF, u16* __restrict__ HB)
{
    constexpr int K = INF;
    __shared__ u16 ldsA[128 * 64];
    __shared__ u16 ldsB[128 * 64];
    const int tid = threadIdx.x, wid = tid >> 6, lane = tid & 63;
    const int wr = wid >> 1, wc = wid & 1;
    const int row0 = blockIdx.x * 128, col0 = blockIdx.y * 128;

    f32x4 acc[4][4];
#pragma unroll
    for (int m = 0; m < 4; ++m)
#pragma unroll
        for (int n = 0; n < 4; ++n) acc[m][n] = (f32x4){0.f, 0.f, 0.f, 0.f};

    const int srow = lane >> 3;
    const int ssw  = (lane & 7) ^ srow;

    for (int ks = 0; ks < K / 64; ++ks) {
        const int k0 = ks * 64;
#pragma unroll
        for (int q = 0; q < 4; ++q) {
            const int c = q * 4 + wid, row = c * 8 + srow;
            gload_lds16(A + (size_t)(row0 + row) * K + k0 + ssw * 8, ldsA + c * 512);
        }
#pragma unroll
        for (int q = 0; q < 4; ++q) {
            const int c = q * 4 + wid, row = c * 8 + srow;
            gload_lds16(B + (size_t)(col0 + row) * K + k0 + ssw * 8, ldsB + c * 512);
        }
        __syncthreads();
        const bf16x8* A8 = (const bf16x8*)ldsA;
        const bf16x8* B8 = (const bf16x8*)ldsB;
        bf16x8 af[4][2], bfr[4][2];
#pragma unroll
        for (int m = 0; m < 4; ++m) {
            const int ar = wr * 64 + m * 16 + (lane & 15);
#pragma unroll
            for (int ks2 = 0; ks2 < 2; ++ks2)
                af[m][ks2] = A8[ar * 8 + ((ks2 * 4 + (lane >> 4)) ^ (ar & 7))];
        }
#pragma unroll
        for (int n = 0; n < 4; ++n) {
            const int br = wc * 64 + n * 16 + (lane & 15);
#pragma unroll
            for (int ks2 = 0; ks2 < 2; ++ks2)
                bfr[n][ks2] = B8[br * 8 + ((ks2 * 4 + (lane >> 4)) ^ (br & 7))];
        }
#pragma unroll
        for (int ks2 = 0; ks2 < 2; ++ks2)
#pragma unroll
            for (int m = 0; m < 4; ++m)
#pragma unroll
                for (int n = 0; n < 4; ++n)
                    acc[m][n] = __builtin_amdgcn_mfma_f32_16x16x32_bf16(
                        af[m][ks2], bfr[n][ks2], acc[m][n], 0, 0, 0);
        __syncthreads();
    }
#pragma unroll
    for (int m = 0; m < 4; ++m)
#pragma unroll
        for (int n = 0; n < 4; ++n) {
            const int col = col0 + wc * 64 + n * 16 + (lane & 15);
            if (col < PCAT) {
#pragma unroll
                for (int r = 0; r < 4; ++r) {
                    const int row = row0 + wr * 64 + m * 16 + (lane >> 4) * 4 + r;
                    const float v = acc[m][n][r];
                    HF[(size_t)row * PCAT + col] = v;
                    HB[(size_t)row * PCAT + col] = f32_to_bf16(v);
                }
            }
        }
}

// ---------------- mega kernel: head GEMM+sumexp  ||  C0/C1 streaming sumexp ----------------
// head section (tile 128x128, K=1024) — per-(col-tile, wc-half) partial store.
// NOTE: two waves (wc=0/1) cover the same 128 rows -> each gets its own slot
// (ct*2+wc); a plain shared slot would lose half the columns (round-5 bug).
static __device__ void head_section(int rb, int ct,
                                    const u16* __restrict__ A, const u16* __restrict__ B,
                                    const int* __restrict__ tgt,
                                    float* __restrict__ SEHp, float* __restrict__ TL,
                                    u16* ldsA, u16* ldsB, int* sth)
{
    constexpr int K = INF;
    const int tid = threadIdx.x, wid = tid >> 6, lane = tid & 63;
    const int wr = wid >> 1, wc = wid & 1;
    const int row0 = rb * 128, col0 = ct * 128;

    if (tid < 128) {
        int t = tgt[row0 + tid];
        sth[tid] = (t < 0) ? 0 : (t < C0_LO ? t : (t < C0_HI ? C0_LO : C0_LO + 1));
    }

    f32x4 acc[4][4];
#pragma unroll
    for (int m = 0; m < 4; ++m)
#pragma unroll
        for (int n = 0; n < 4; ++n) acc[m][n] = (f32x4){0.f, 0.f, 0.f, 0.f};

    const int srow = lane >> 3;
    const int ssw  = (lane & 7) ^ srow;

    for (int ks = 0; ks < K / 64; ++ks) {
        const int k0 = ks * 64;
#pragma unroll
        for (int q = 0; q < 4; ++q) {
            const int c = q * 4 + wid, row = c * 8 + srow;
            gload_lds16(A + (size_t)(row0 + row) * K + k0 + ssw * 8, ldsA + c * 512);
        }
#pragma unroll
        for (int q = 0; q < 4; ++q) {
            const int c = q * 4 + wid, row = c * 8 + srow;
            gload_lds16(B + (size_t)(col0 + row) * K + k0 + ssw * 8, ldsB + c * 512);
        }
        __syncthreads();
        const bf16x8* A8 = (const bf16x8*)ldsA;
        const bf16x8* B8 = (const bf16x8*)ldsB;
        bf16x8 af[4][2], bfr[4][2];
#pragma unroll
        for (int m = 0; m < 4; ++m) {
            const int ar = wr * 64 + m * 16 + (lane & 15);
#pragma unroll
            for (int ks2 = 0; ks2 < 2; ++ks2)
                af[m][ks2] = A8[ar * 8 + ((ks2 * 4 + (lane >> 4)) ^ (ar & 7))];
        }
#pragma unroll
        for (int n = 0; n < 4; ++n) {
            const int br = wc * 64 + n * 16 + (lane & 15);
#pragma unroll
            for (int ks2 = 0; ks2 < 2; ++ks2)
                bfr[n][ks2] = B8[br * 8 + ((ks2 * 4 + (lane >> 4)) ^ (br & 7))];
        }
#pragma unroll
        for (int ks2 = 0; ks2 < 2; ++ks2)
#pragma unroll
            for (int m = 0; m < 4; ++m)
#pragma unroll
                for (int n = 0; n < 4; ++n)
                    acc[m][n] = __builtin_amdgcn_mfma_f32_16x16x32_bf16(
                        af[m][ks2], bfr[n][ks2], acc[m][n], 0, 0, 0);
        __syncthreads();
    }

    const int slot = ct * 2 + wc;
#pragma unroll
    for (int m = 0; m < 4; ++m) {
        f32x4 rs = (f32x4){0.f, 0.f, 0.f, 0.f};
#pragma unroll
        for (int n = 0; n < 4; ++n) {
            const int cls = col0 + wc * 64 + n * 16 + (lane & 15);
            if (cls < HEAD_N) {
#pragma unroll
                for (int r = 0; r < 4; ++r) {
                    rs[r] += fast_exp2(acc[m][n][r]);
                    const int lrow = wr * 64 + m * 16 + (lane >> 4) * 4 + r;
                    if (sth[lrow] == cls) TL[row0 + lrow] = acc[m][n][r];
                }
            }
        }
#pragma unroll
        for (int msk = 1; msk < 16; msk <<= 1)
#pragma unroll
            for (int r = 0; r < 4; ++r) rs[r] += __shfl_xor(rs[r], msk, 64);
        if ((lane & 15) == 0) {
            const int rbase = row0 + wr * 64 + m * 16 + (lane >> 4) * 4;
#pragma unroll
            for (int r = 0; r < 4; ++r) SEHp[(size_t)slot * NR + rbase + r] = rs[r];
        }
    }
}

// cluster section: compacted rows in registers, W streamed via double-buffered LDS
// (each wave owns a disjoint 32-row range -> plain partial stores are safe here)
template<int K, int CT>
static __device__ void sumexp_section(const u16* __restrict__ Hbase, int ldh,
                                      const int* __restrict__ list,
                                      const u16* __restrict__ W,
                                      int nreal, int ntiles, int tps,
                                      int rb, int split, float* __restrict__ SEp,
                                      u16* lds)
{
    constexpr int MSETS = 2;
    constexpr int NKF   = K / 32;
    constexpr int SLOTS = K / 8;
    constexpr int CHUNKS = CT * K * 2 / 4096;
    constexpr int RPC   = 256 / SLOTS;
    constexpr int NT    = CT / 16;

    const int tid = threadIdx.x, wid = tid >> 6, lane = tid & 63;
    const int row0 = rb * 128 + wid * 32;

    const int t0 = split * tps;
    const int t1 = min(t0 + tps, ntiles);

    bf16x8 afr[MSETS][NKF];
#pragma unroll
    for (int m = 0; m < MSETS; ++m) {
        const int orow = list[row0 + m * 16 + (lane & 15)];
        const u16* hr = Hbase + (size_t)orow * ldh + (lane >> 4) * 8;
#pragma unroll
        for (int kf = 0; kf < NKF; ++kf)
            afr[m][kf] = *(const bf16x8*)(hr + kf * 32);
    }

    float rs[MSETS][4];
#pragma unroll
    for (int m = 0; m < MSETS; ++m)
#pragma unroll
        for (int r = 0; r < 4; ++r) rs[m][r] = 0.f;

    const int trow  = tid / SLOTS;
    const int swoff = ((tid % SLOTS) ^ (trow & 7)) * 8;

    auto STAGE = [&](int t, int buf) {
        const u16* wb = W + (size_t)t * CT * K + (size_t)trow * K + swoff;
        u16* lb = lds + buf * (CT * K) + wid * 512;
#pragma unroll
        for (int c = 0; c < CHUNKS; ++c)
            gload_lds16(wb + (size_t)c * RPC * K, lb + c * 2048);
    };

    int cur = 0;
    STAGE(t0, 0);
    __syncthreads();

    for (int t = t0; t < t1; ++t) {
        if (t + 1 < t1) STAGE(t + 1, cur ^ 1);
        const bf16x8* B8 = (const bf16x8*)(lds + cur * (CT * K));
        const bool full = (t + 1) * CT <= nreal;
#pragma unroll
        for (int n = 0; n < NT; ++n) {
            const int br = n * 16 + (lane & 15);
            bf16x8 bfr[NKF];
#pragma unroll
            for (int kf = 0; kf < NKF; ++kf)
                bfr[kf] = B8[br * SLOTS + ((kf * 4 + (lane >> 4)) ^ (br & 7))];
            f32x4 acc[MSETS];
#pragma unroll
            for (int m = 0; m < MSETS; ++m) acc[m] = (f32x4){0.f, 0.f, 0.f, 0.f};
#pragma unroll
            for (int m = 0; m < MSETS; ++m)
#pragma unroll
                for (int kf = 0; kf < NKF; ++kf)
                    acc[m] = __builtin_amdgcn_mfma_f32_16x16x32_bf16(
                        afr[m][kf], bfr[kf], acc[m], 0, 0, 0);
            if (full || (t * CT + n * 16 + (lane & 15)) < nreal) {
#pragma unroll
                for (int m = 0; m < MSETS; ++m)
#pragma unroll
                    for (int r = 0; r < 4; ++r) rs[m][r] += fast_exp2(acc[m][r]);
            }
        }
        __syncthreads();
        cur ^= 1;
    }

#pragma unroll
    for (int msk = 1; msk < 16; msk <<= 1)
#pragma unroll
        for (int m = 0; m < MSETS; ++m)
#pragma unroll
            for (int r = 0; r < 4; ++r) rs[m][r] += __shfl_xor(rs[m][r], msk, 64);
    if ((lane & 15) == 0) {
        const int rbase = row0 + (lane >> 4) * 4;
#pragma unroll
        for (int m = 0; m < MSETS; ++m)
#pragma unroll
            for (int r = 0; r < 4; ++r)
                SEp[(size_t)split * NR + rbase + m * 16 + r] = rs[m][r];
    }
}

__launch_bounds__(256, 3)
__global__ void mega_kernel(const u16* __restrict__ xb, const u16* __restrict__ wcatb,
                            const u16* __restrict__ hcatb,
                            const u16* __restrict__ o0b, const u16* __restrict__ o1b,
                            const int* __restrict__ tgt,
                            const int* __restrict__ c0list, const int* __restrict__ c1list,
                            const int* __restrict__ cnts,
                            float* __restrict__ SEHp, float* __restrict__ TL,
                            float* __restrict__ C0p, float* __restrict__ C1p)
{
    __shared__ u16 smem[2][8192];
    __shared__ int sth[128];
    const int bid = blockIdx.x;

    if (bid < 1024) {
        if ((bid & 1) == 0) {
            const int h = bid >> 1;            // 0..511
            head_section(h >> 4, h & 15, xb, wcatb, tgt, SEHp, TL,
                         smem[0], smem[1], sth);
        } else {
            const int c = bid >> 1;            // 0..511 ; real slots: rb*S1+split
            const int rb = c / S1, split = c - rb * S1;
            if (rb * 128 < cnts[3])
                sumexp_section<K1, 128>(hcatb + 256, PCAT, c1list, o1b,
                                        C1_N, C1_NP / 128, 32, rb, split, C1p, smem[0]);
        }
    } else {
        const int idx = bid - 1024;            // 0..511
        const int rb = idx >> 4, split = idx & 15;
        if (rb * 128 < cnts[2])
            sumexp_section<K0, 32>(hcatb, PCAT, c0list, o0b,
                                   C0_N, C0_N / 32, 16, rb, split, C0p, smem[0]);
    }
}

// ---------------- per-row epilogue: one wave per row ----------------
__global__ void epilogue_kernel(const int* __restrict__ tgt, const float* __restrict__ tl,
                                const float* __restrict__ out0, const float* __restrict__ out1,
                                const float* __restrict__ hcatf,
                                const float* __restrict__ SEHp, const float* __restrict__ C0p,
                                const float* __restrict__ C1p, const int* __restrict__ crow,
                                float* __restrict__ rowlogp, float* __restrict__ rowvalid) {
    const int wid = threadIdx.x >> 6, lane = threadIdx.x & 63;
    const int r = blockIdx.x * 4 + wid;
    const int t = tgt[r];
    const bool valid = (t != IGNORE);
    const int tc = valid ? t : 0;
    const int band = (tc < C0_LO) ? 0 : (tc < C0_HI) ? 1 : 2;
    const int cr = crow[r];

    float p2 = 0.f;
    if (band == 1) {
        const float* hr = hcatf + (size_t)r * PCAT;
        const float* crp = out0 + (size_t)(tc - C0_LO) * K0;
        for (int k = lane; k < K0; k += 64) p2 += hr[k] * crp[k];
    } else if (band == 2) {
        p2 = hcatf[(size_t)r * PCAT + 256 + lane] * out1[(size_t)(tc - C0_HI) * K1 + lane];
    }
#pragma unroll
    for (int msk = 32; msk >= 1; msk >>= 1) p2 += __shfl_xor(p2, msk, 64);

    float hp = (lane < NHP) ? SEHp[(size_t)lane * NR + r] : 0.f;
    float cp = 0.f;
    if (band == 1 && lane < S0) cp = C0p[(size_t)lane * NR + cr];
    if (band == 2 && lane < S1) cp = C1p[(size_t)lane * NR + cr];
#pragma unroll
    for (int msk = 1; msk < 32; msk <<= 1) {
        hp += __shfl_xor(hp, msk, 64);
        cp += __shfl_xor(cp, msk, 64);
    }

    if (lane == 0) {
        float logp = LN2 * tl[r] - __logf(hp);
        if (band != 0) logp += p2 - __logf(cp);
        rowlogp[r]  = valid ? logp : 0.f;
        rowvalid[r] = valid ? 1.f : 0.f;
    }
}

// ---------------- deterministic final reduce ----------------
__global__ void final_reduce(const float* __restrict__ rowlogp,
                             const float* __restrict__ rowvalid, float* __restrict__ out) {
    __shared__ float sl[256], sv[256];
    const int tid = threadIdx.x;
    float a = 0.f, b = 0.f;
    for (int i = tid; i < NR; i += 256) { a += rowlogp[i]; b += rowvalid[i]; }
    sl[tid] = a; sv[tid] = b;
    __syncthreads();
    for (int s = 128; s > 0; s >>= 1) {
        if (tid < s) { sl[tid] += sl[tid + s]; sv[tid] += sv[tid + s]; }
        __syncthreads();
    }
    if (tid == 0) out[0] = -sl[0] / sv[0];
}

extern "C" void kernel_launch(void* const* d_in, const int* in_sizes, int n_in,
                              void* d_out, int out_size, void* d_ws, size_t ws_size,
                              hipStream_t stream) {
    const float* x      = (const float*)d_in[0];
    const int*   tgt    = (const int*)d_in[1];
    const float* head_w = (const float*)d_in[2];
    const float* proj0  = (const float*)d_in[3];
    const float* out0   = (const float*)d_in[4];
    const float* proj1  = (const float*)d_in[5];
    const float* out1   = (const float*)d_in[6];
    float* loss = (float*)d_out;

    char* base = (char*)d_ws;
    size_t off = 0;
    auto alloc = [&](size_t bytes) { char* p = base + off; off += (bytes + 255) & ~(size_t)255; return p; };

    u16* xb    = (u16*)alloc((size_t)NR * INF * 2);
    u16* wcatb = (u16*)alloc((size_t)WCAT_R * INF * 2);
    u16* o0b   = (u16*)alloc((size_t)C0_N * K0 * 2);
    u16* o1b   = (u16*)alloc((size_t)C1_NP * K1 * 2);
    float* hcatf = (float*)alloc((size_t)NR * PCAT * 4);
    u16*   hcatb = (u16*)alloc((size_t)NR * PCAT * 2);
    float* SEHp = (float*)alloc((size_t)NHP * NR * 4);
    float* C0p  = (float*)alloc((size_t)S0 * NR * 4);
    float* C1p  = (float*)alloc((size_t)S1 * NR * 4);
    float* tl   = (float*)alloc((size_t)NR * 4);
    int* c0list = (int*)alloc((size_t)(NR + 128) * 4);
    int* c1list = (int*)alloc((size_t)(NR + 128) * 4);
    int* crow   = (int*)alloc((size_t)NR * 4);
    int* cnts   = (int*)alloc(4 * 4);
    float* rowlogp  = (float*)alloc((size_t)NR * 4);
    float* rowvalid = (float*)alloc((size_t)NR * 4);

    compact_kernel<<<1, 1024, 0, stream>>>(tgt, c0list, c1list, crow, cnts);

    CvtSegs segs;
    segs.s[0] = x;      segs.d[0] = xb;                              segs.n8[0] = NR * INF / 8;      segs.sc[0] = 1.0f;
    segs.s[1] = head_w; segs.d[1] = wcatb;                           segs.n8[1] = HEAD_N * INF / 8;  segs.sc[1] = LOG2E;
    segs.s[2] = proj0;  segs.d[2] = wcatb + (size_t)HEAD_NP * INF;   segs.n8[2] = 256 * INF / 8;     segs.sc[2] = 1.0f;
    segs.s[3] = proj1;  segs.d[3] = wcatb + (size_t)(HEAD_NP + 256) * INF; segs.n8[3] = 64 * INF / 8; segs.sc[3] = 1.0f;
    segs.s[4] = out0;   segs.d[4] = o0b;                             segs.n8[4] = C0_N * K0 / 8;     segs.sc[4] = LOG2E;
    segs.s[5] = out1;   segs.d[5] = o1b;                             segs.n8[5] = C1_N * K1 / 8;     segs.sc[5] = LOG2E;
    cvt_multi<<<2048, 256, 0, stream>>>(segs);

    // hcat = X @ [proj0;proj1]^T  (f32 for epilogue dot, bf16 for cluster GEMMs)
    proj_tile<<<dim3(32, PCAT_P / 128), 256, 0, stream>>>(xb, wcatb + (size_t)HEAD_NP * INF, hcatf, hcatb);

    // head GEMM+sumexp (even bids) || C1 sumexp (odd bids) || C0 sumexp (tail)
    mega_kernel<<<MEGA_GRID, 256, 0, stream>>>(xb, wcatb, hcatb, o0b, o1b, tgt,
                                               c0list, c1list, cnts, SEHp, tl, C0p, C1p);

    epilogue_kernel<<<NR / 4, 256, 0, stream>>>(tgt, tl, out0, out1, hcatf,
                                                SEHp, C0p, C1p, crow, rowlogp, rowvalid);
    final_reduce<<<1, 256, 0, stream>>>(rowlogp, rowvalid, loss);
    (void)in_sizes; (void)n_in; (void)out_size; (void)ws_size;
}